// Round 4
// baseline (196.788 us; speedup 1.0000x reference)
//
#include <hip/hip_runtime.h>
#include <math.h>

#define THREADS 512
#define WAVES (THREADS / 64)
#define LOG2E 1.4426950408889634f
#define LN2   0.6931471805599453f

__device__ __forceinline__ float fexp2(float x) { return __builtin_amdgcn_exp2f(x); }

// Online-LSE update in base-2 domain: chain k tracks m = max(t), s = sum 2^(t-m).
#define LSE2_UPD(mk, sk, t)                                   \
    {                                                         \
        float nm_ = fmaxf((mk), (t));                         \
        (sk) = (sk) * fexp2((mk) - nm_) + fexp2((t) - nm_);   \
        (mk) = nm_;                                           \
    }

#define LSE2_MERGE(ma, sa, mb, sb)                                    \
    {                                                                 \
        float nm_ = fmaxf((ma), (mb));                                \
        (sa) = (sa) * fexp2((ma) - nm_) + (sb) * fexp2((mb) - nm_);   \
        (ma) = nm_;                                                   \
    }

// One block per row, single pass, 4 independent float4 loads in flight per
// iteration (64 B/lane/iter). 8 base-2 online-LSE chains + fused window sum.
__global__ __launch_bounds__(THREADS, 4)
void ce_row_kernel(const float* __restrict__ x,
                   const int* __restrict__ targets,
                   const int* __restrict__ positives,
                   float* __restrict__ row_out,
                   int N)
{
    const int b = blockIdx.x;
    const float4* row4 = reinterpret_cast<const float4*>(x + (size_t)b * N);
    const int t0 = targets[b];
    const unsigned wlen = (unsigned)positives[b];   // window length - 1
    const int n4 = N >> 2;

    float m0 = -INFINITY, m1 = -INFINITY, m2 = -INFINITY, m3 = -INFINITY;
    float m4 = -INFINITY, m5 = -INFINITY, m6 = -INFINITY, m7 = -INFINITY;
    float s0 = 0.f, s1 = 0.f, s2 = 0.f, s3 = 0.f;
    float s4 = 0.f, s5 = 0.f, s6 = 0.f, s7 = 0.f;
    float wsum = 0.f;

    int i = threadIdx.x;
    for (; i + 3 * THREADS < n4; i += 4 * THREADS) {
        // Issue all 4 loads before any compute (independent addresses).
        float4 a = row4[i];
        float4 c = row4[i + THREADS];
        float4 e = row4[i + 2 * THREADS];
        float4 g = row4[i + 3 * THREADS];

        const unsigned ja = (unsigned)((i               << 2) - t0);
        const unsigned jc = (unsigned)(((i +     THREADS) << 2) - t0);
        const unsigned je = (unsigned)(((i + 2 * THREADS) << 2) - t0);
        const unsigned jg = (unsigned)(((i + 3 * THREADS) << 2) - t0);

        // Base-2 transform (1 mul/elem), then chain updates.
        float ta0 = a.x * LOG2E, ta1 = a.y * LOG2E, ta2 = a.z * LOG2E, ta3 = a.w * LOG2E;
        float tc0 = c.x * LOG2E, tc1 = c.y * LOG2E, tc2 = c.z * LOG2E, tc3 = c.w * LOG2E;
        LSE2_UPD(m0, s0, ta0); LSE2_UPD(m1, s1, ta1);
        LSE2_UPD(m2, s2, ta2); LSE2_UPD(m3, s3, ta3);
        LSE2_UPD(m4, s4, tc0); LSE2_UPD(m5, s5, tc1);
        LSE2_UPD(m6, s6, tc2); LSE2_UPD(m7, s7, tc3);

        float te0 = e.x * LOG2E, te1 = e.y * LOG2E, te2 = e.z * LOG2E, te3 = e.w * LOG2E;
        float tg0 = g.x * LOG2E, tg1 = g.y * LOG2E, tg2 = g.z * LOG2E, tg3 = g.w * LOG2E;
        LSE2_UPD(m0, s0, te0); LSE2_UPD(m1, s1, te1);
        LSE2_UPD(m2, s2, te2); LSE2_UPD(m3, s3, te3);
        LSE2_UPD(m4, s4, tg0); LSE2_UPD(m5, s5, tg1);
        LSE2_UPD(m6, s6, tg2); LSE2_UPD(m7, s7, tg3);

        // Window sums (unsigned-range predicate; wraparound math is exact).
        wsum += (ja     <= wlen) ? a.x : 0.f;
        wsum += (ja + 1 <= wlen) ? a.y : 0.f;
        wsum += (ja + 2 <= wlen) ? a.z : 0.f;
        wsum += (ja + 3 <= wlen) ? a.w : 0.f;
        wsum += (jc     <= wlen) ? c.x : 0.f;
        wsum += (jc + 1 <= wlen) ? c.y : 0.f;
        wsum += (jc + 2 <= wlen) ? c.z : 0.f;
        wsum += (jc + 3 <= wlen) ? c.w : 0.f;
        wsum += (je     <= wlen) ? e.x : 0.f;
        wsum += (je + 1 <= wlen) ? e.y : 0.f;
        wsum += (je + 2 <= wlen) ? e.z : 0.f;
        wsum += (je + 3 <= wlen) ? e.w : 0.f;
        wsum += (jg     <= wlen) ? g.x : 0.f;
        wsum += (jg + 1 <= wlen) ? g.y : 0.f;
        wsum += (jg + 2 <= wlen) ? g.z : 0.f;
        wsum += (jg + 3 <= wlen) ? g.w : 0.f;
    }
    for (; i < n4; i += THREADS) {  // generic tail (not taken for 32768/512)
        float4 a = row4[i];
        const unsigned ja = (unsigned)((i << 2) - t0);
        float ta0 = a.x * LOG2E, ta1 = a.y * LOG2E, ta2 = a.z * LOG2E, ta3 = a.w * LOG2E;
        LSE2_UPD(m0, s0, ta0); LSE2_UPD(m1, s1, ta1);
        LSE2_UPD(m2, s2, ta2); LSE2_UPD(m3, s3, ta3);
        wsum += (ja     <= wlen) ? a.x : 0.f;
        wsum += (ja + 1 <= wlen) ? a.y : 0.f;
        wsum += (ja + 2 <= wlen) ? a.z : 0.f;
        wsum += (ja + 3 <= wlen) ? a.w : 0.f;
    }

    // Merge the 8 chains into (m0, s0).
    LSE2_MERGE(m0, s0, m1, s1); LSE2_MERGE(m2, s2, m3, s3);
    LSE2_MERGE(m4, s4, m5, s5); LSE2_MERGE(m6, s6, m7, s7);
    LSE2_MERGE(m0, s0, m2, s2); LSE2_MERGE(m4, s4, m6, s6);
    LSE2_MERGE(m0, s0, m4, s4);

    // 64-lane butterfly reduction.
    #pragma unroll
    for (int off = 32; off > 0; off >>= 1) {
        float om = __shfl_xor(m0, off, 64);
        float os = __shfl_xor(s0, off, 64);
        float ow = __shfl_xor(wsum, off, 64);
        LSE2_MERGE(m0, s0, om, os);
        wsum += ow;
    }

    // Cross-wave combine via LDS.
    __shared__ float sm[WAVES], ss[WAVES], sw[WAVES];
    const int wave = threadIdx.x >> 6;
    const int lane = threadIdx.x & 63;
    if (lane == 0) { sm[wave] = m0; ss[wave] = s0; sw[wave] = wsum; }
    __syncthreads();

    if (threadIdx.x == 0) {
        m0 = sm[0]; s0 = ss[0]; wsum = sw[0];
        #pragma unroll
        for (int w = 1; w < WAVES; ++w) {
            LSE2_MERGE(m0, s0, sm[w], ss[w]);
            wsum += sw[w];
        }
        const float count = (float)(wlen + 1u);
        // natural-log LSE = ln2 * (m2 + log2(s))
        row_out[b] = LN2 * (m0 + log2f(s0)) - wsum / count;
    }
}

// Mean over B per-row values -> out[0].
__global__ __launch_bounds__(256)
void ce_reduce_kernel(const float* __restrict__ row_vals,
                      float* __restrict__ out, int B, float invB)
{
    float acc = 0.f;
    for (int i = threadIdx.x; i < B; i += 256) acc += row_vals[i];
    #pragma unroll
    for (int off = 32; off > 0; off >>= 1) acc += __shfl_xor(acc, off, 64);

    __shared__ float sb[4];
    const int wave = threadIdx.x >> 6;
    const int lane = threadIdx.x & 63;
    if (lane == 0) sb[wave] = acc;
    __syncthreads();
    if (threadIdx.x == 0)
        out[0] = (sb[0] + sb[1] + sb[2] + sb[3]) * invB;
}

extern "C" void kernel_launch(void* const* d_in, const int* in_sizes, int n_in,
                              void* d_out, int out_size, void* d_ws, size_t ws_size,
                              hipStream_t stream) {
    const float* inputs    = (const float*)d_in[0];
    const int*   targets   = (const int*)d_in[1];
    const int*   positives = (const int*)d_in[2];
    float* out = (float*)d_out;
    float* row_vals = (float*)d_ws;     // B floats of scratch

    const int B = in_sizes[1];          // 1024
    const int N = in_sizes[0] / B;      // 32768

    ce_row_kernel<<<B, THREADS, 0, stream>>>(inputs, targets, positives,
                                             row_vals, N);
    ce_reduce_kernel<<<1, 256, 0, stream>>>(row_vals, out, B, 1.0f / (float)B);
}

// Round 5
// 193.844 us; speedup vs baseline: 1.0152x; 1.0152x over previous
//
#include <hip/hip_runtime.h>
#include <math.h>

#define THREADS 512
#define WAVES (THREADS / 64)
#define LOG2E 1.4426950408889634f
#define LN2   0.6931471805599453f

__device__ __forceinline__ float fexp2(float x) { return __builtin_amdgcn_exp2f(x); }

// Online-LSE update in base-2 domain: chain k tracks m = max(t), s = sum 2^(t-m).
#define LSE2_UPD(mk, sk, t)                                   \
    {                                                         \
        float nm_ = fmaxf((mk), (t));                         \
        (sk) = (sk) * fexp2((mk) - nm_) + fexp2((t) - nm_);   \
        (mk) = nm_;                                           \
    }

#define LSE2_MERGE(ma, sa, mb, sb)                                    \
    {                                                                 \
        float nm_ = fmaxf((ma), (mb));                                \
        (sa) = (sa) * fexp2((ma) - nm_) + (sb) * fexp2((mb) - nm_);   \
        (ma) = nm_;                                                   \
    }

// One block per row, single circular pass starting at a per-block rotation
// (breaks HBM channel camping from the 128 KiB power-of-2 row stride).
// 4 independent float4 loads in flight; 8 base-2 online-LSE chains;
// fused window sum. Writes per_sample[b] to row_out.
__global__ __launch_bounds__(THREADS, 4)
void ce_row_kernel(const float* __restrict__ x,
                   const int* __restrict__ targets,
                   const int* __restrict__ positives,
                   float* __restrict__ row_out,
                   int N)
{
    const int b = blockIdx.x;
    const float4* row4 = reinterpret_cast<const float4*>(x + (size_t)b * N);
    const int t0 = targets[b];
    const unsigned wlen = (unsigned)positives[b];   // window length - 1
    const int n4 = N >> 2;                          // 8192 (power of 2)
    const int mask = n4 - 1;
    const int rot = (b * 2731) & mask;              // per-block phase rotation

    float m0 = -INFINITY, m1 = -INFINITY, m2 = -INFINITY, m3 = -INFINITY;
    float m4 = -INFINITY, m5 = -INFINITY, m6 = -INFINITY, m7 = -INFINITY;
    float s0 = 0.f, s1 = 0.f, s2 = 0.f, s3 = 0.f;
    float s4 = 0.f, s5 = 0.f, s6 = 0.f, s7 = 0.f;
    float wsum = 0.f;

    int i = threadIdx.x;
    for (; i + 3 * THREADS < n4; i += 4 * THREADS) {
        const int ia = (i               + rot) & mask;
        const int ic = (i +     THREADS + rot) & mask;
        const int ie = (i + 2 * THREADS + rot) & mask;
        const int ig = (i + 3 * THREADS + rot) & mask;

        // Issue all 4 loads before any compute (independent addresses).
        float4 a = row4[ia];
        float4 c = row4[ic];
        float4 e = row4[ie];
        float4 g = row4[ig];

        const unsigned ja = (unsigned)((ia << 2) - t0);
        const unsigned jc = (unsigned)((ic << 2) - t0);
        const unsigned je = (unsigned)((ie << 2) - t0);
        const unsigned jg = (unsigned)((ig << 2) - t0);

        // Base-2 transform (1 mul/elem), then chain updates.
        float ta0 = a.x * LOG2E, ta1 = a.y * LOG2E, ta2 = a.z * LOG2E, ta3 = a.w * LOG2E;
        float tc0 = c.x * LOG2E, tc1 = c.y * LOG2E, tc2 = c.z * LOG2E, tc3 = c.w * LOG2E;
        LSE2_UPD(m0, s0, ta0); LSE2_UPD(m1, s1, ta1);
        LSE2_UPD(m2, s2, ta2); LSE2_UPD(m3, s3, ta3);
        LSE2_UPD(m4, s4, tc0); LSE2_UPD(m5, s5, tc1);
        LSE2_UPD(m6, s6, tc2); LSE2_UPD(m7, s7, tc3);

        float te0 = e.x * LOG2E, te1 = e.y * LOG2E, te2 = e.z * LOG2E, te3 = e.w * LOG2E;
        float tg0 = g.x * LOG2E, tg1 = g.y * LOG2E, tg2 = g.z * LOG2E, tg3 = g.w * LOG2E;
        LSE2_UPD(m0, s0, te0); LSE2_UPD(m1, s1, te1);
        LSE2_UPD(m2, s2, te2); LSE2_UPD(m3, s3, te3);
        LSE2_UPD(m4, s4, tg0); LSE2_UPD(m5, s5, tg1);
        LSE2_UPD(m6, s6, tg2); LSE2_UPD(m7, s7, tg3);

        // Window sums (unsigned-range predicate; wraparound math is exact).
        wsum += (ja     <= wlen) ? a.x : 0.f;
        wsum += (ja + 1 <= wlen) ? a.y : 0.f;
        wsum += (ja + 2 <= wlen) ? a.z : 0.f;
        wsum += (ja + 3 <= wlen) ? a.w : 0.f;
        wsum += (jc     <= wlen) ? c.x : 0.f;
        wsum += (jc + 1 <= wlen) ? c.y : 0.f;
        wsum += (jc + 2 <= wlen) ? c.z : 0.f;
        wsum += (jc + 3 <= wlen) ? c.w : 0.f;
        wsum += (je     <= wlen) ? e.x : 0.f;
        wsum += (je + 1 <= wlen) ? e.y : 0.f;
        wsum += (je + 2 <= wlen) ? e.z : 0.f;
        wsum += (je + 3 <= wlen) ? e.w : 0.f;
        wsum += (jg     <= wlen) ? g.x : 0.f;
        wsum += (jg + 1 <= wlen) ? g.y : 0.f;
        wsum += (jg + 2 <= wlen) ? g.z : 0.f;
        wsum += (jg + 3 <= wlen) ? g.w : 0.f;
    }
    for (; i < n4; i += THREADS) {  // generic tail (not taken for 32768/512)
        const int ia = (i + rot) & mask;
        float4 a = row4[ia];
        const unsigned ja = (unsigned)((ia << 2) - t0);
        float ta0 = a.x * LOG2E, ta1 = a.y * LOG2E, ta2 = a.z * LOG2E, ta3 = a.w * LOG2E;
        LSE2_UPD(m0, s0, ta0); LSE2_UPD(m1, s1, ta1);
        LSE2_UPD(m2, s2, ta2); LSE2_UPD(m3, s3, ta3);
        wsum += (ja     <= wlen) ? a.x : 0.f;
        wsum += (ja + 1 <= wlen) ? a.y : 0.f;
        wsum += (ja + 2 <= wlen) ? a.z : 0.f;
        wsum += (ja + 3 <= wlen) ? a.w : 0.f;
    }

    // Merge the 8 chains into (m0, s0).
    LSE2_MERGE(m0, s0, m1, s1); LSE2_MERGE(m2, s2, m3, s3);
    LSE2_MERGE(m4, s4, m5, s5); LSE2_MERGE(m6, s6, m7, s7);
    LSE2_MERGE(m0, s0, m2, s2); LSE2_MERGE(m4, s4, m6, s6);
    LSE2_MERGE(m0, s0, m4, s4);

    // 64-lane butterfly reduction.
    #pragma unroll
    for (int off = 32; off > 0; off >>= 1) {
        float om = __shfl_xor(m0, off, 64);
        float os = __shfl_xor(s0, off, 64);
        float ow = __shfl_xor(wsum, off, 64);
        LSE2_MERGE(m0, s0, om, os);
        wsum += ow;
    }

    // Cross-wave combine via LDS.
    __shared__ float sm[WAVES], ss[WAVES], sw[WAVES];
    const int wave = threadIdx.x >> 6;
    const int lane = threadIdx.x & 63;
    if (lane == 0) { sm[wave] = m0; ss[wave] = s0; sw[wave] = wsum; }
    __syncthreads();

    if (threadIdx.x == 0) {
        m0 = sm[0]; s0 = ss[0]; wsum = sw[0];
        #pragma unroll
        for (int w = 1; w < WAVES; ++w) {
            LSE2_MERGE(m0, s0, sm[w], ss[w]);
            wsum += sw[w];
        }
        const float count = (float)(wlen + 1u);
        // natural-log LSE = ln2 * (m + log2(s))
        row_out[b] = LN2 * (m0 + log2f(s0)) - wsum / count;
    }
}

// Mean over B per-row values -> out[0].
__global__ __launch_bounds__(256)
void ce_reduce_kernel(const float* __restrict__ row_vals,
                      float* __restrict__ out, int B, float invB)
{
    float acc = 0.f;
    for (int i = threadIdx.x; i < B; i += 256) acc += row_vals[i];
    #pragma unroll
    for (int off = 32; off > 0; off >>= 1) acc += __shfl_xor(acc, off, 64);

    __shared__ float sb[4];
    const int wave = threadIdx.x >> 6;
    const int lane = threadIdx.x & 63;
    if (lane == 0) sb[wave] = acc;
    __syncthreads();
    if (threadIdx.x == 0)
        out[0] = (sb[0] + sb[1] + sb[2] + sb[3]) * invB;
}

extern "C" void kernel_launch(void* const* d_in, const int* in_sizes, int n_in,
                              void* d_out, int out_size, void* d_ws, size_t ws_size,
                              hipStream_t stream) {
    const float* inputs    = (const float*)d_in[0];
    const int*   targets   = (const int*)d_in[1];
    const int*   positives = (const int*)d_in[2];
    float* out = (float*)d_out;
    float* row_vals = (float*)d_ws;     // B floats of scratch

    const int B = in_sizes[1];          // 1024
    const int N = in_sizes[0] / B;      // 32768

    ce_row_kernel<<<B, THREADS, 0, stream>>>(inputs, targets, positives,
                                             row_vals, N);
    ce_reduce_kernel<<<1, 256, 0, stream>>>(row_vals, out, B, 1.0f / (float)B);
}